// Round 2
// baseline (1046.217 us; speedup 1.0000x reference)
//
#include <hip/hip_runtime.h>

#define D 64

// --- zero a float region (graph-capture-safe replacement for hipMemsetAsync) ---
__global__ void zero_kernel(float* __restrict__ p, long long n) {
    long long i = (long long)blockIdx.x * blockDim.x + threadIdx.x;
    long long stride = (long long)gridDim.x * blockDim.x;
    for (; i < n; i += stride) p[i] = 0.0f;
}

// --- degree count: one thread per edge ---
__global__ void count_kernel(const int* __restrict__ dst,
                             float* __restrict__ cnt, int E) {
    int e = blockIdx.x * blockDim.x + threadIdx.x;
    if (e < E) atomicAdd(&cnt[dst[e]], 1.0f);
}

// --- aggregation: one wave per edge, lane = feature; coalesced gather + scatter-atomic ---
__global__ void agg_kernel(const float* __restrict__ feat,
                           const int* __restrict__ src,
                           const int* __restrict__ dst,
                           float* __restrict__ agg, int E) {
    long long idx = (long long)blockIdx.x * blockDim.x + threadIdx.x;
    int e = (int)(idx >> 6);
    int f = (int)(idx & 63);
    if (e < E) {
        int s = src[e];
        int d = dst[e];
        atomicAdd(&agg[(long long)d * D + f], feat[(long long)s * D + f]);
    }
}

// --- fused linear: out[i] = relu?( Wl @ (agg[i]/max(cnt,1)) + Wr @ xin[i] + b ) ---
// Wave-per-node. Lane f holds rows f of Wl/Wr stationary in VGPRs; node features are
// wave-uniform -> scalar loads -> inner loop is v_fmac with SGPR operand.
__global__ __launch_bounds__(256) void lin_kernel(
    const float* __restrict__ agg, const float* __restrict__ cnt,
    const float* __restrict__ xin,
    const float* __restrict__ Wl, const float* __restrict__ Wr,
    const float* __restrict__ bias,
    float* __restrict__ out, int N, int relu) {
    int lane = threadIdx.x & 63;
    int wid = blockIdx.x * (blockDim.x >> 6) + (threadIdx.x >> 6);
    int nwaves = gridDim.x * (blockDim.x >> 6);

    // stationary weight rows for this lane (16KB matrices, L1/L2-resident)
    float wl[D], wr[D];
#pragma unroll
    for (int k = 0; k < D; ++k) {
        wl[k] = Wl[lane * D + k];
        wr[k] = Wr[lane * D + k];
    }
    float bv = bias[lane];

    for (int node = wid; node < N; node += nwaves) {
        int un = __builtin_amdgcn_readfirstlane(node);
        const float* __restrict__ ar = agg + (long long)un * D;
        const float* __restrict__ xr = xin + (long long)un * D;
        float accA = 0.f, accX = 0.f;
#pragma unroll
        for (int k = 0; k < D; ++k) {
            accA += wl[k] * ar[k];
            accX += wr[k] * xr[k];
        }
        float c = cnt[un];
        float inv = 1.0f / fmaxf(c, 1.0f);
        float v = accA * inv + accX + bv;
        if (relu) v = fmaxf(v, 0.0f);
        out[(long long)un * D + lane] = v;
    }
}

extern "C" void kernel_launch(void* const* d_in, const int* in_sizes, int n_in,
                              void* d_out, int out_size, void* d_ws, size_t ws_size,
                              hipStream_t stream) {
    const float* x    = (const float*)d_in[0];
    const int* ei     = (const int*)d_in[1];   // integer inputs arrive as int32
    const float* W1l  = (const float*)d_in[2];
    const float* W1r  = (const float*)d_in[3];
    const float* b1   = (const float*)d_in[4];
    const float* W2l  = (const float*)d_in[5];
    const float* W2r  = (const float*)d_in[6];
    const float* b2   = (const float*)d_in[7];

    const int E = in_sizes[1] / 2;
    const int N = in_sizes[0] / D;
    const int* src  = ei;
    const int* dstp = ei + E;

    // workspace layout: [cnt (N floats, padded)] [agg (N*D floats)]
    char* ws = (char*)d_ws;
    size_t cntPad = (((size_t)N * 4) + 4095) & ~(size_t)4095;
    float* cnt = (float*)ws;
    float* agg = (float*)(ws + cntPad);
    size_t aggBytes = (size_t)N * D * sizeof(float);

    float* out = (float*)d_out;
    float* h   = out;  // layer-1 output aliases d_out (safe: lin2 reads row un before writing row un)

    // zero cnt+agg (contiguous region) — ws is poisoned 0xAA before every timed call
    long long zn = (long long)(cntPad / 4) + (long long)N * D;
    zero_kernel<<<2048, 256, 0, stream>>>((float*)ws, zn);

    count_kernel<<<(E + 255) / 256, 256, 0, stream>>>(dstp, cnt, E);

    long long tot = (long long)E * D;
    int aggGrid = (int)((tot + 255) / 256);

    // layer 1
    agg_kernel<<<aggGrid, 256, 0, stream>>>(x, src, dstp, agg, E);
    lin_kernel<<<1024, 256, 0, stream>>>(agg, cnt, x, W1l, W1r, b1, h, N, 1);

    // layer 2 (re-zero agg only)
    zero_kernel<<<2048, 256, 0, stream>>>(agg, (long long)N * D);
    agg_kernel<<<aggGrid, 256, 0, stream>>>(h, src, dstp, agg, E);
    lin_kernel<<<1024, 256, 0, stream>>>(agg, cnt, h, W2l, W2r, b2, out, N, 0);
}

// Round 3
// 618.186 us; speedup vs baseline: 1.6924x; 1.6924x over previous
//
#include <hip/hip_runtime.h>

#define D 64

// ---------- utility: zero int region ----------
__global__ void zeroi_kernel(int* __restrict__ p, int n) {
    int i = blockIdx.x * blockDim.x + threadIdx.x;
    if (i < n) p[i] = 0;
}

// ---------- CSR build step 1: degree histogram ----------
__global__ void hist_kernel(const int* __restrict__ dst, int* __restrict__ deg, int E) {
    int e = blockIdx.x * blockDim.x + threadIdx.x;
    if (e < E) atomicAdd(&deg[dst[e]], 1);
}

// ---------- CSR build step 2a: per-block sums ----------
__global__ void scan1_kernel(const int* __restrict__ deg, int* __restrict__ partial, int N) {
    __shared__ int sh[256];
    int i = blockIdx.x * 256 + threadIdx.x;
    int v = (i < N) ? deg[i] : 0;
    sh[threadIdx.x] = v;
    __syncthreads();
    for (int off = 128; off > 0; off >>= 1) {
        if (threadIdx.x < off) sh[threadIdx.x] += sh[threadIdx.x + off];
        __syncthreads();
    }
    if (threadIdx.x == 0) partial[blockIdx.x] = sh[0];
}

// ---------- CSR build step 2b: exclusive scan of block sums (NB <= 512) ----------
__global__ void scan2_kernel(int* __restrict__ partial, int NB) {
    __shared__ int sh[512];
    int tid = threadIdx.x;
    int v = (tid < NB) ? partial[tid] : 0;
    sh[tid] = v;
    __syncthreads();
    for (int off = 1; off < 512; off <<= 1) {
        int t = (tid >= off) ? sh[tid - off] : 0;
        __syncthreads();
        sh[tid] += t;
        __syncthreads();
    }
    if (tid < NB) partial[tid] = sh[tid] - v;  // exclusive
}

// ---------- CSR build step 2c: block-local exclusive scan + offset -> rowptr, cursor ----------
__global__ void scan3_kernel(const int* __restrict__ deg, const int* __restrict__ partial,
                             int* __restrict__ rowptr, int* __restrict__ cursor, int N, int E) {
    __shared__ int sh[256];
    int tid = threadIdx.x;
    int i = blockIdx.x * 256 + tid;
    int v = (i < N) ? deg[i] : 0;
    sh[tid] = v;
    __syncthreads();
    for (int off = 1; off < 256; off <<= 1) {
        int t = (tid >= off) ? sh[tid - off] : 0;
        __syncthreads();
        sh[tid] += t;
        __syncthreads();
    }
    int incl = sh[tid];
    int base = partial[blockIdx.x];
    if (i < N) {
        int e = base + incl - v;
        rowptr[i] = e;
        cursor[i] = e;
    }
    if (i == N - 1) rowptr[N] = base + incl;  // == E
}

// ---------- CSR build step 3: scatter src ids into buckets ----------
__global__ void scatter_kernel(const int* __restrict__ src, const int* __restrict__ dst,
                               int* __restrict__ cursor, int* __restrict__ csr, int E) {
    int e = blockIdx.x * blockDim.x + threadIdx.x;
    if (e < E) {
        int pos = atomicAdd(&cursor[dst[e]], 1);
        csr[pos] = src[e];
    }
}

// ---------- aggregation: one wave per node, lane = feature, no atomics ----------
__global__ __launch_bounds__(256) void agg_kernel(
    const float* __restrict__ feat, const int* __restrict__ rowptr,
    const int* __restrict__ csr, float* __restrict__ mean, int N) {
    int lane = threadIdx.x & 63;
    int wid = blockIdx.x * (blockDim.x >> 6) + (threadIdx.x >> 6);
    int nwaves = gridDim.x * (blockDim.x >> 6);

    for (int node = wid; node < N; node += nwaves) {
        int un = __builtin_amdgcn_readfirstlane(node);
        int beg = rowptr[un];
        int end = rowptr[un + 1];
        float sum = 0.0f;
        int j = beg;
        // 4-deep independent gathers to hide latency
        for (; j + 4 <= end; j += 4) {
            int s0 = csr[j], s1 = csr[j + 1], s2 = csr[j + 2], s3 = csr[j + 3];
            float f0 = feat[(long long)s0 * D + lane];
            float f1 = feat[(long long)s1 * D + lane];
            float f2 = feat[(long long)s2 * D + lane];
            float f3 = feat[(long long)s3 * D + lane];
            sum += f0 + f1 + f2 + f3;
        }
        for (; j < end; ++j) sum += feat[(long long)csr[j] * D + lane];
        float c = (float)(end - beg);
        mean[(long long)un * D + lane] = sum / fmaxf(c, 1.0f);
    }
}

// ---------- fused linear: out[i] = relu?( Wl @ mean_i + Wr @ x_i + b ) ----------
__global__ __launch_bounds__(256) void lin_kernel(
    const float* __restrict__ mean, const float* __restrict__ xin,
    const float* __restrict__ Wl, const float* __restrict__ Wr,
    const float* __restrict__ bias,
    float* __restrict__ out, int N, int relu) {
    int lane = threadIdx.x & 63;
    int wid = blockIdx.x * (blockDim.x >> 6) + (threadIdx.x >> 6);
    int nwaves = gridDim.x * (blockDim.x >> 6);

    float wl[D], wr[D];
#pragma unroll
    for (int k = 0; k < D; ++k) {
        wl[k] = Wl[lane * D + k];
        wr[k] = Wr[lane * D + k];
    }
    float bv = bias[lane];

    for (int node = wid; node < N; node += nwaves) {
        int un = __builtin_amdgcn_readfirstlane(node);
        const float* __restrict__ ar = mean + (long long)un * D;
        const float* __restrict__ xr = xin + (long long)un * D;
        float accA = 0.f, accX = 0.f;
#pragma unroll
        for (int k = 0; k < D; ++k) {
            accA += wl[k] * ar[k];
            accX += wr[k] * xr[k];
        }
        float v = accA + accX + bv;
        if (relu) v = fmaxf(v, 0.0f);
        out[(long long)un * D + lane] = v;
    }
}

extern "C" void kernel_launch(void* const* d_in, const int* in_sizes, int n_in,
                              void* d_out, int out_size, void* d_ws, size_t ws_size,
                              hipStream_t stream) {
    const float* x   = (const float*)d_in[0];
    const int* ei    = (const int*)d_in[1];   // int32 edge index
    const float* W1l = (const float*)d_in[2];
    const float* W1r = (const float*)d_in[3];
    const float* b1  = (const float*)d_in[4];
    const float* W2l = (const float*)d_in[5];
    const float* W2r = (const float*)d_in[6];
    const float* b2  = (const float*)d_in[7];

    const int E = in_sizes[1] / 2;
    const int N = in_sizes[0] / D;
    const int* src  = ei;
    const int* dstp = ei + E;
    const int NB = (N + 255) / 256;  // 391 for N=100k (must be <= 512)

    // workspace layout
    char* ws = (char*)d_ws;
    size_t off = 0;
    auto alloc = [&](size_t bytes) { void* p = ws + off; off = (off + bytes + 255) & ~(size_t)255; return p; };
    int* deg     = (int*)alloc((size_t)N * 4);
    int* rowptr  = (int*)alloc((size_t)(N + 1) * 4);
    int* cursor  = (int*)alloc((size_t)N * 4);
    int* partial = (int*)alloc((size_t)NB * 4);
    int* csr     = (int*)alloc((size_t)E * 4);
    float* mean  = (float*)alloc((size_t)N * D * 4);

    float* out = (float*)d_out;
    float* h   = out;  // layer-1 output aliases d_out (lin2 reads row un before writing row un)

    // ---- CSR build (per call; ws re-poisoned every launch) ----
    zeroi_kernel<<<(N + 255) / 256, 256, 0, stream>>>(deg, N);
    hist_kernel<<<(E + 255) / 256, 256, 0, stream>>>(dstp, deg, E);
    scan1_kernel<<<NB, 256, 0, stream>>>(deg, partial, N);
    scan2_kernel<<<1, 512, 0, stream>>>(partial, NB);
    scan3_kernel<<<NB, 256, 0, stream>>>(deg, partial, rowptr, cursor, N, E);
    scatter_kernel<<<(E + 255) / 256, 256, 0, stream>>>(src, dstp, cursor, csr, E);

    // ---- layer 1 ----
    agg_kernel<<<4096, 256, 0, stream>>>(x, rowptr, csr, mean, N);
    lin_kernel<<<1024, 256, 0, stream>>>(mean, x, W1l, W1r, b1, h, N, 1);

    // ---- layer 2 (reuse CSR) ----
    agg_kernel<<<4096, 256, 0, stream>>>(h, rowptr, csr, mean, N);
    lin_kernel<<<1024, 256, 0, stream>>>(mean, h, W2l, W2r, b2, out, N, 0);
}

// Round 4
// 450.357 us; speedup vs baseline: 2.3231x; 1.3727x over previous
//
#include <hip/hip_runtime.h>

#define D 64
#define BSHIFT 9              // 512 nodes per bucket
#define BNODES (1 << BSHIFT)
#define NBK_MAX 512           // supports N up to 262144

// ---------- zero int region ----------
__global__ void zeroi_kernel(int* __restrict__ p, int n) {
    int i = blockIdx.x * blockDim.x + threadIdx.x;
    if (i < n) p[i] = 0;
}

// ---------- phase 1: per-(bucket,group) histogram. group = blockIdx&7 (~XCD) ----------
__global__ __launch_bounds__(256) void hist2_kernel(const int* __restrict__ dst,
                                                    int* __restrict__ cnt2,
                                                    int E, int NBK, int CE) {
    __shared__ int lh[NBK_MAX];
    for (int k = threadIdx.x; k < NBK; k += 256) lh[k] = 0;
    __syncthreads();
    int b = blockIdx.x, g = b & 7;
    int beg = b * CE, end = min(beg + CE, E);
    for (int e = beg + threadIdx.x; e < end; e += 256)
        atomicAdd(&lh[dst[e] >> BSHIFT], 1);
    __syncthreads();
    for (int k = threadIdx.x; k < NBK; k += 256)
        if (lh[k]) atomicAdd(&cnt2[(k << 3) | g], lh[k]);
}

// ---------- phase 2: exclusive scan of cnt2[NBK*8] -> cur2 (mutable) + bstart (stable) ----------
__global__ __launch_bounds__(256) void scan2k_kernel(const int* __restrict__ cnt2,
                                                     int* __restrict__ cur2,
                                                     int* __restrict__ bstart, int NBK) {
    __shared__ int s[256];
    int n = NBK << 3;
    int tid = threadIdx.x;
    int base = tid * 8;
    int loc[8];
    int sum = 0;
    for (int j = 0; j < 8; ++j) {
        int idx = base + j;
        int v = (idx < n) ? cnt2[idx] : 0;
        loc[j] = sum;          // exclusive within thread
        sum += v;
    }
    s[tid] = sum;
    __syncthreads();
    for (int off = 1; off < 256; off <<= 1) {
        int t = (tid >= off) ? s[tid - off] : 0;
        __syncthreads();
        s[tid] += t;
        __syncthreads();
    }
    int ebase = s[tid] - sum;  // exclusive across threads
    for (int j = 0; j < 8; ++j) {
        int idx = base + j;
        if (idx < n) cur2[idx] = ebase + loc[j];
    }
    // bucket k starts at element k*8 — owned by thread t=k (8 elems/thread)
    if (tid < NBK) bstart[tid] = ebase;   // == excl scan at idx tid*8
    if (tid == 0) bstart[NBK] = s[255];   // == E
}

// ---------- phase 3: scatter packed records into per-(bucket,group) sub-regions ----------
// record = src | (dst & (BNODES-1)) << 17   (requires N <= 131072)
__global__ __launch_bounds__(256) void binscatter_kernel(
    const int* __restrict__ src, const int* __restrict__ dst,
    int* __restrict__ cur2, unsigned int* __restrict__ pairs,
    int E, int NBK, int CE) {
    __shared__ int lh[NBK_MAX];
    __shared__ int lbase[NBK_MAX];
    for (int k = threadIdx.x; k < NBK; k += 256) lh[k] = 0;
    __syncthreads();
    int b = blockIdx.x, g = b & 7;
    int beg = b * CE, end = min(beg + CE, E);
    // pass 1: local counts
    for (int e = beg + threadIdx.x; e < end; e += 256)
        atomicAdd(&lh[dst[e] >> BSHIFT], 1);
    __syncthreads();
    // reserve runs in this group's sub-regions; reset lh for rank assignment
    for (int k = threadIdx.x; k < NBK; k += 256) {
        int c = lh[k];
        if (c) lbase[k] = atomicAdd(&cur2[(k << 3) | g], c);
        lh[k] = 0;
    }
    __syncthreads();
    // pass 2: place records
    for (int e = beg + threadIdx.x; e < end; e += 256) {
        int d = dst[e];
        int k = d >> BSHIFT;
        int r = atomicAdd(&lh[k], 1);
        pairs[lbase[k] + r] = (unsigned int)src[e] | ((unsigned int)(d & (BNODES - 1)) << 17);
    }
}

// ---------- phase 4: one workgroup per bucket -> rowptr (dense) + csr (bucket-local) ----------
__global__ __launch_bounds__(256) void csr_build_kernel(
    const unsigned int* __restrict__ pairs, const int* __restrict__ bstart,
    int* __restrict__ rowptr, int* __restrict__ csr, int N, int NBK) {
    __shared__ int lcnt[BNODES];
    __shared__ int lofs[BNODES];
    __shared__ int s[256];
    int k = blockIdx.x;
    int tid = threadIdx.x;
    int node0 = k << BSHIFT;
    int nnodes = min(BNODES, N - node0);
    int rbeg = bstart[k], rend = bstart[k + 1];

    for (int j = tid; j < BNODES; j += 256) lcnt[j] = 0;
    __syncthreads();
    for (int i = rbeg + tid; i < rend; i += 256)
        atomicAdd(&lcnt[pairs[i] >> 17], 1);
    __syncthreads();
    // exclusive scan of lcnt[0..511]: pair-sums then Hillis-Steele over 256
    int v0 = lcnt[2 * tid], v1 = lcnt[2 * tid + 1];
    int ps = v0 + v1;
    s[tid] = ps;
    __syncthreads();
    for (int off = 1; off < 256; off <<= 1) {
        int t = (tid >= off) ? s[tid - off] : 0;
        __syncthreads();
        s[tid] += t;
        __syncthreads();
    }
    int ebase = s[tid] - ps;
    lofs[2 * tid] = ebase;
    lofs[2 * tid + 1] = ebase + v0;
    __syncthreads();
    // rowptr (dense write) + cursors (reuse lcnt)
    for (int j = tid; j < nnodes; j += 256) {
        int p = rbeg + lofs[j];
        rowptr[node0 + j] = p;
        lcnt[j] = p;
    }
    if (k == NBK - 1 && tid == 0) rowptr[N] = rend;
    __syncthreads();
    // scatter src ids into exact csr positions (writes stay in this bucket's region)
    for (int i = rbeg + tid; i < rend; i += 256) {
        unsigned int rec = pairs[i];
        int j = rec >> 17;
        int pos = atomicAdd(&lcnt[j], 1);
        csr[pos] = (int)(rec & 0x1FFFFu);
    }
}

// ---------- aggregation: one wave per node, lane = feature, no atomics ----------
__global__ __launch_bounds__(256) void agg_kernel(
    const float* __restrict__ feat, const int* __restrict__ rowptr,
    const int* __restrict__ csr, float* __restrict__ mean, int N) {
    int lane = threadIdx.x & 63;
    int wid = blockIdx.x * (blockDim.x >> 6) + (threadIdx.x >> 6);
    int nwaves = gridDim.x * (blockDim.x >> 6);

    for (int node = wid; node < N; node += nwaves) {
        int un = __builtin_amdgcn_readfirstlane(node);
        int beg = rowptr[un];
        int end = rowptr[un + 1];
        float sum = 0.0f;
        int j = beg;
        for (; j + 4 <= end; j += 4) {
            int s0 = csr[j], s1 = csr[j + 1], s2 = csr[j + 2], s3 = csr[j + 3];
            float f0 = feat[(long long)s0 * D + lane];
            float f1 = feat[(long long)s1 * D + lane];
            float f2 = feat[(long long)s2 * D + lane];
            float f3 = feat[(long long)s3 * D + lane];
            sum += f0 + f1 + f2 + f3;
        }
        for (; j < end; ++j) sum += feat[(long long)csr[j] * D + lane];
        float c = (float)(end - beg);
        mean[(long long)un * D + lane] = sum / fmaxf(c, 1.0f);
    }
}

// ---------- fused linear: out[i] = relu?( Wl @ mean_i + Wr @ x_i + b ) ----------
__global__ __launch_bounds__(256) void lin_kernel(
    const float* __restrict__ mean, const float* __restrict__ xin,
    const float* __restrict__ Wl, const float* __restrict__ Wr,
    const float* __restrict__ bias,
    float* __restrict__ out, int N, int relu) {
    int lane = threadIdx.x & 63;
    int wid = blockIdx.x * (blockDim.x >> 6) + (threadIdx.x >> 6);
    int nwaves = gridDim.x * (blockDim.x >> 6);

    float wl[D], wr[D];
#pragma unroll
    for (int k = 0; k < D; ++k) {
        wl[k] = Wl[lane * D + k];
        wr[k] = Wr[lane * D + k];
    }
    float bv = bias[lane];

    for (int node = wid; node < N; node += nwaves) {
        int un = __builtin_amdgcn_readfirstlane(node);
        const float* __restrict__ ar = mean + (long long)un * D;
        const float* __restrict__ xr = xin + (long long)un * D;
        float accA = 0.f, accX = 0.f;
#pragma unroll
        for (int k = 0; k < D; ++k) {
            accA += wl[k] * ar[k];
            accX += wr[k] * xr[k];
        }
        float v = accA + accX + bv;
        if (relu) v = fmaxf(v, 0.0f);
        out[(long long)un * D + lane] = v;
    }
}

extern "C" void kernel_launch(void* const* d_in, const int* in_sizes, int n_in,
                              void* d_out, int out_size, void* d_ws, size_t ws_size,
                              hipStream_t stream) {
    const float* x   = (const float*)d_in[0];
    const int* ei    = (const int*)d_in[1];
    const float* W1l = (const float*)d_in[2];
    const float* W1r = (const float*)d_in[3];
    const float* b1  = (const float*)d_in[4];
    const float* W2l = (const float*)d_in[5];
    const float* W2r = (const float*)d_in[6];
    const float* b2  = (const float*)d_in[7];

    const int E = in_sizes[1] / 2;
    const int N = in_sizes[0] / D;     // requires N <= 131072 for 17-bit packing
    const int* src  = ei;
    const int* dstp = ei + E;
    const int NBK = (N + BNODES - 1) >> BSHIFT;   // 196 for N=100k
    const int G1 = 512;                           // binning blocks (group = b&7)
    const int CE = (E + G1 - 1) / G1;

    // workspace layout
    char* ws = (char*)d_ws;
    size_t off = 0;
    auto alloc = [&](size_t bytes) { void* p = ws + off; off = (off + bytes + 255) & ~(size_t)255; return p; };
    int* cnt2          = (int*)alloc((size_t)(NBK * 8) * 4);
    int* cur2          = (int*)alloc((size_t)(NBK * 8) * 4);
    int* bstart        = (int*)alloc((size_t)(NBK + 1) * 4);
    int* rowptr        = (int*)alloc((size_t)(N + 1) * 4);
    unsigned int* pairs = (unsigned int*)alloc((size_t)E * 4);
    int* csr           = (int*)alloc((size_t)E * 4);
    float* mean        = (float*)alloc((size_t)N * D * 4);

    float* out = (float*)d_out;
    float* h   = out;  // layer-1 output aliases d_out (lin2 reads row un before writing row un)

    // ---- CSR build: bucket counting sort, dense writes ----
    zeroi_kernel<<<(NBK * 8 + 255) / 256, 256, 0, stream>>>(cnt2, NBK * 8);
    hist2_kernel<<<G1, 256, 0, stream>>>(dstp, cnt2, E, NBK, CE);
    scan2k_kernel<<<1, 256, 0, stream>>>(cnt2, cur2, bstart, NBK);
    binscatter_kernel<<<G1, 256, 0, stream>>>(src, dstp, cur2, pairs, E, NBK, CE);
    csr_build_kernel<<<NBK, 256, 0, stream>>>(pairs, bstart, rowptr, csr, N, NBK);

    // ---- layer 1 ----
    agg_kernel<<<4096, 256, 0, stream>>>(x, rowptr, csr, mean, N);
    lin_kernel<<<1024, 256, 0, stream>>>(mean, x, W1l, W1r, b1, h, N, 1);

    // ---- layer 2 (reuse CSR) ----
    agg_kernel<<<4096, 256, 0, stream>>>(h, rowptr, csr, mean, N);
    lin_kernel<<<1024, 256, 0, stream>>>(mean, h, W2l, W2r, b2, out, N, 0);
}

// Round 5
// 332.896 us; speedup vs baseline: 3.1428x; 1.3528x over previous
//
#include <hip/hip_runtime.h>

#define D 64
#define BSHIFT 9              // 512 nodes per bucket
#define BNODES (1 << BSHIFT)
#define NBK_MAX 512           // supports N up to 262144

// ---------- zero int region ----------
__global__ void zeroi_kernel(int* __restrict__ p, int n) {
    int i = blockIdx.x * blockDim.x + threadIdx.x;
    if (i < n) p[i] = 0;
}

// ---------- phase 1: per-(bucket,group) histogram. group = blockIdx&7 (~XCD) ----------
__global__ __launch_bounds__(256) void hist2_kernel(const int* __restrict__ dst,
                                                    int* __restrict__ cnt2,
                                                    int E, int NBK, int CE) {
    __shared__ int lh[NBK_MAX];
    for (int k = threadIdx.x; k < NBK; k += 256) lh[k] = 0;
    __syncthreads();
    int b = blockIdx.x, g = b & 7;
    int beg = b * CE, end = min(beg + CE, E);
    for (int e = beg + threadIdx.x; e < end; e += 256)
        atomicAdd(&lh[dst[e] >> BSHIFT], 1);
    __syncthreads();
    for (int k = threadIdx.x; k < NBK; k += 256)
        if (lh[k]) atomicAdd(&cnt2[(k << 3) | g], lh[k]);
}

// ---------- phase 2: exclusive scan of cnt2[NBK*8] -> cur2 (mutable) + bstart (stable) ----------
__global__ __launch_bounds__(256) void scan2k_kernel(const int* __restrict__ cnt2,
                                                     int* __restrict__ cur2,
                                                     int* __restrict__ bstart, int NBK) {
    __shared__ int s[256];
    int n = NBK << 3;
    int tid = threadIdx.x;
    int base = tid * 8;
    int loc[8];
    int sum = 0;
    for (int j = 0; j < 8; ++j) {
        int idx = base + j;
        int v = (idx < n) ? cnt2[idx] : 0;
        loc[j] = sum;          // exclusive within thread
        sum += v;
    }
    s[tid] = sum;
    __syncthreads();
    for (int off = 1; off < 256; off <<= 1) {
        int t = (tid >= off) ? s[tid - off] : 0;
        __syncthreads();
        s[tid] += t;
        __syncthreads();
    }
    int ebase = s[tid] - sum;  // exclusive across threads
    for (int j = 0; j < 8; ++j) {
        int idx = base + j;
        if (idx < n) cur2[idx] = ebase + loc[j];
    }
    if (tid < NBK) bstart[tid] = ebase;   // == excl scan at idx tid*8
    if (tid == 0) bstart[NBK] = s[255];   // == E
}

// ---------- phase 3: scatter packed records into per-(bucket,group) sub-regions ----------
// record = src | (dst & (BNODES-1)) << 17   (requires N <= 131072)
__global__ __launch_bounds__(256) void binscatter_kernel(
    const int* __restrict__ src, const int* __restrict__ dst,
    int* __restrict__ cur2, unsigned int* __restrict__ pairs,
    int E, int NBK, int CE) {
    __shared__ int lh[NBK_MAX];
    __shared__ int lbase[NBK_MAX];
    for (int k = threadIdx.x; k < NBK; k += 256) lh[k] = 0;
    __syncthreads();
    int b = blockIdx.x, g = b & 7;
    int beg = b * CE, end = min(beg + CE, E);
    for (int e = beg + threadIdx.x; e < end; e += 256)
        atomicAdd(&lh[dst[e] >> BSHIFT], 1);
    __syncthreads();
    for (int k = threadIdx.x; k < NBK; k += 256) {
        int c = lh[k];
        if (c) lbase[k] = atomicAdd(&cur2[(k << 3) | g], c);
        lh[k] = 0;
    }
    __syncthreads();
    for (int e = beg + threadIdx.x; e < end; e += 256) {
        int d = dst[e];
        int k = d >> BSHIFT;
        int r = atomicAdd(&lh[k], 1);
        pairs[lbase[k] + r] = (unsigned int)src[e] | ((unsigned int)(d & (BNODES - 1)) << 17);
    }
}

// ---------- phase 4: one workgroup per bucket -> rowptr (dense) + csr (bucket-local) ----------
__global__ __launch_bounds__(256) void csr_build_kernel(
    const unsigned int* __restrict__ pairs, const int* __restrict__ bstart,
    int* __restrict__ rowptr, int* __restrict__ csr, int N, int NBK) {
    __shared__ int lcnt[BNODES];
    __shared__ int lofs[BNODES];
    __shared__ int s[256];
    int k = blockIdx.x;
    int tid = threadIdx.x;
    int node0 = k << BSHIFT;
    int nnodes = min(BNODES, N - node0);
    int rbeg = bstart[k], rend = bstart[k + 1];

    for (int j = tid; j < BNODES; j += 256) lcnt[j] = 0;
    __syncthreads();
    for (int i = rbeg + tid; i < rend; i += 256)
        atomicAdd(&lcnt[pairs[i] >> 17], 1);
    __syncthreads();
    int v0 = lcnt[2 * tid], v1 = lcnt[2 * tid + 1];
    int ps = v0 + v1;
    s[tid] = ps;
    __syncthreads();
    for (int off = 1; off < 256; off <<= 1) {
        int t = (tid >= off) ? s[tid - off] : 0;
        __syncthreads();
        s[tid] += t;
        __syncthreads();
    }
    int ebase = s[tid] - ps;
    lofs[2 * tid] = ebase;
    lofs[2 * tid + 1] = ebase + v0;
    __syncthreads();
    for (int j = tid; j < nnodes; j += 256) {
        int p = rbeg + lofs[j];
        rowptr[node0 + j] = p;
        lcnt[j] = p;
    }
    if (k == NBK - 1 && tid == 0) rowptr[N] = rend;
    __syncthreads();
    for (int i = rbeg + tid; i < rend; i += 256) {
        unsigned int rec = pairs[i];
        int j = rec >> 17;
        int pos = atomicAdd(&lcnt[j], 1);
        csr[pos] = (int)(rec & 0x1FFFFu);
    }
}

// ---------- aggregation: one wave per node, lane = feature, no atomics ----------
__global__ __launch_bounds__(256) void agg_kernel(
    const float* __restrict__ feat, const int* __restrict__ rowptr,
    const int* __restrict__ csr, float* __restrict__ mean, int N) {
    int lane = threadIdx.x & 63;
    int wid = blockIdx.x * (blockDim.x >> 6) + (threadIdx.x >> 6);
    int nwaves = gridDim.x * (blockDim.x >> 6);

    for (int node = wid; node < N; node += nwaves) {
        int un = __builtin_amdgcn_readfirstlane(node);
        int beg = rowptr[un];
        int end = rowptr[un + 1];
        float sum = 0.0f;
        int j = beg;
        for (; j + 4 <= end; j += 4) {
            int s0 = csr[j], s1 = csr[j + 1], s2 = csr[j + 2], s3 = csr[j + 3];
            float f0 = feat[(long long)s0 * D + lane];
            float f1 = feat[(long long)s1 * D + lane];
            float f2 = feat[(long long)s2 * D + lane];
            float f3 = feat[(long long)s3 * D + lane];
            sum += f0 + f1 + f2 + f3;
        }
        for (; j < end; ++j) sum += feat[(long long)csr[j] * D + lane];
        float c = (float)(end - beg);
        mean[(long long)un * D + lane] = sum / fmaxf(c, 1.0f);
    }
}

// ---------- fused linear as LDS-tiled GEMM ----------
// out[n][f] = relu?( sum_k Wl[f][k]*mean[n][k] + sum_k Wr[f][k]*x[n][k] + b[f] )
// A = [mean | x]  (K=128), Wt[k][f] = k<64 ? Wl[f][k] : Wr[f][k-64]
// block: 256 threads, persistent; tile = 64 nodes x 64 outputs; thread = 4 nodes x 4 outputs
#define WT_S 68    // Wt row stride (floats): 272B = 17*16 -> b128-aligned
#define AN_S 132   // An row stride (floats): 528B = 33*16 -> b128-aligned
__global__ __launch_bounds__(256) void lin_gemm_kernel(
    const float* __restrict__ mean, const float* __restrict__ xin,
    const float* __restrict__ Wl, const float* __restrict__ Wr,
    const float* __restrict__ bias,
    float* __restrict__ out, int N, int relu) {
    __shared__ float Wt[128 * WT_S];
    __shared__ float An[64 * AN_S];
    int tid = threadIdx.x;

    // ---- stage Wt (transposed weights), once per block ----
    // 8192 floats = 2048 float4; iter i: L = i*256+tid; m = Wl/Wr; f = row; kq = k-quad
#pragma unroll
    for (int i = 0; i < 8; ++i) {
        int L = i * 256 + tid;
        int m = L >> 10;
        int r = L & 1023;
        int f = r >> 4;
        int kq = r & 15;
        const float* Wsrc = m ? Wr : Wl;
        float4 v = *(const float4*)(Wsrc + f * 64 + kq * 4);
        int kb = m * 64 + kq * 4;
        Wt[(kb + 0) * WT_S + f] = v.x;
        Wt[(kb + 1) * WT_S + f] = v.y;
        Wt[(kb + 2) * WT_S + f] = v.z;
        Wt[(kb + 3) * WT_S + f] = v.w;
    }

    int f0  = (tid & 15) * 4;   // output quad
    int nl0 = (tid >> 4) * 4;   // node quad (local)
    float4 bv = *(const float4*)(bias + f0);

    int numTiles = (N + 63) >> 6;
    for (int t = blockIdx.x; t < numTiles; t += gridDim.x) {
        int node0 = t << 6;
        __syncthreads();  // previous compute done before re-staging An
        // ---- stage An: 64 nodes x 128 k; coalesced float4 global, b128 LDS writes ----
#pragma unroll
        for (int i = 0; i < 8; ++i) {
            int L = i * 256 + tid;
            int kq = L & 15;            // 16 quads = 64 floats of one source row
            int h  = (L >> 4) & 1;      // 0 = mean, 1 = x
            int nl = L >> 5;            // node local
            int n = node0 + nl;
            float4 v = make_float4(0.f, 0.f, 0.f, 0.f);
            if (n < N) {
                const float* srcp = (h ? xin : mean) + (long long)n * D + kq * 4;
                v = *(const float4*)srcp;
            }
            *(float4*)&An[nl * AN_S + h * 64 + kq * 4] = v;
        }
        __syncthreads();
        // ---- compute: 4 nodes x 4 outputs per thread ----
        float acc00=0,acc01=0,acc02=0,acc03=0;
        float acc10=0,acc11=0,acc12=0,acc13=0;
        float acc20=0,acc21=0,acc22=0,acc23=0;
        float acc30=0,acc31=0,acc32=0,acc33=0;
#pragma unroll 4
        for (int k = 0; k < 128; ++k) {
            float4 w = *(const float4*)&Wt[k * WT_S + f0];
            float a0 = An[(nl0 + 0) * AN_S + k];
            float a1 = An[(nl0 + 1) * AN_S + k];
            float a2 = An[(nl0 + 2) * AN_S + k];
            float a3 = An[(nl0 + 3) * AN_S + k];
            acc00 += a0 * w.x; acc01 += a0 * w.y; acc02 += a0 * w.z; acc03 += a0 * w.w;
            acc10 += a1 * w.x; acc11 += a1 * w.y; acc12 += a1 * w.z; acc13 += a1 * w.w;
            acc20 += a2 * w.x; acc21 += a2 * w.y; acc22 += a2 * w.z; acc23 += a2 * w.w;
            acc30 += a3 * w.x; acc31 += a3 * w.y; acc32 += a3 * w.z; acc33 += a3 * w.w;
        }
        // ---- epilogue: bias (+relu), coalesced float4 stores ----
        float r00=acc00+bv.x, r01=acc01+bv.y, r02=acc02+bv.z, r03=acc03+bv.w;
        float r10=acc10+bv.x, r11=acc11+bv.y, r12=acc12+bv.z, r13=acc13+bv.w;
        float r20=acc20+bv.x, r21=acc21+bv.y, r22=acc22+bv.z, r23=acc23+bv.w;
        float r30=acc30+bv.x, r31=acc31+bv.y, r32=acc32+bv.z, r33=acc33+bv.w;
        if (relu) {
            r00=fmaxf(r00,0.f); r01=fmaxf(r01,0.f); r02=fmaxf(r02,0.f); r03=fmaxf(r03,0.f);
            r10=fmaxf(r10,0.f); r11=fmaxf(r11,0.f); r12=fmaxf(r12,0.f); r13=fmaxf(r13,0.f);
            r20=fmaxf(r20,0.f); r21=fmaxf(r21,0.f); r22=fmaxf(r22,0.f); r23=fmaxf(r23,0.f);
            r30=fmaxf(r30,0.f); r31=fmaxf(r31,0.f); r32=fmaxf(r32,0.f); r33=fmaxf(r33,0.f);
        }
        int nb = node0 + nl0;
        if (nb + 0 < N) *(float4*)(out + (long long)(nb + 0) * D + f0) = make_float4(r00, r01, r02, r03);
        if (nb + 1 < N) *(float4*)(out + (long long)(nb + 1) * D + f0) = make_float4(r10, r11, r12, r13);
        if (nb + 2 < N) *(float4*)(out + (long long)(nb + 2) * D + f0) = make_float4(r20, r21, r22, r23);
        if (nb + 3 < N) *(float4*)(out + (long long)(nb + 3) * D + f0) = make_float4(r30, r31, r32, r33);
        __syncthreads();  // all reads of An done before next tile restages
    }
}

extern "C" void kernel_launch(void* const* d_in, const int* in_sizes, int n_in,
                              void* d_out, int out_size, void* d_ws, size_t ws_size,
                              hipStream_t stream) {
    const float* x   = (const float*)d_in[0];
    const int* ei    = (const int*)d_in[1];
    const float* W1l = (const float*)d_in[2];
    const float* W1r = (const float*)d_in[3];
    const float* b1  = (const float*)d_in[4];
    const float* W2l = (const float*)d_in[5];
    const float* W2r = (const float*)d_in[6];
    const float* b2  = (const float*)d_in[7];

    const int E = in_sizes[1] / 2;
    const int N = in_sizes[0] / D;     // requires N <= 131072 for 17-bit packing
    const int* src  = ei;
    const int* dstp = ei + E;
    const int NBK = (N + BNODES - 1) >> BSHIFT;   // 196 for N=100k
    const int G1 = 512;
    const int CE = (E + G1 - 1) / G1;

    char* ws = (char*)d_ws;
    size_t off = 0;
    auto alloc = [&](size_t bytes) { void* p = ws + off; off = (off + bytes + 255) & ~(size_t)255; return p; };
    int* cnt2           = (int*)alloc((size_t)(NBK * 8) * 4);
    int* cur2           = (int*)alloc((size_t)(NBK * 8) * 4);
    int* bstart         = (int*)alloc((size_t)(NBK + 1) * 4);
    int* rowptr         = (int*)alloc((size_t)(N + 1) * 4);
    unsigned int* pairs = (unsigned int*)alloc((size_t)E * 4);
    int* csr            = (int*)alloc((size_t)E * 4);
    float* mean         = (float*)alloc((size_t)N * D * 4);

    float* out = (float*)d_out;
    float* h   = out;  // layer-1 output aliases d_out (lin2 stages its h rows to LDS before overwriting)

    // ---- CSR build: bucket counting sort, dense writes ----
    zeroi_kernel<<<(NBK * 8 + 255) / 256, 256, 0, stream>>>(cnt2, NBK * 8);
    hist2_kernel<<<G1, 256, 0, stream>>>(dstp, cnt2, E, NBK, CE);
    scan2k_kernel<<<1, 256, 0, stream>>>(cnt2, cur2, bstart, NBK);
    binscatter_kernel<<<G1, 256, 0, stream>>>(src, dstp, cur2, pairs, E, NBK, CE);
    csr_build_kernel<<<NBK, 256, 0, stream>>>(pairs, bstart, rowptr, csr, N, NBK);

    // ---- layer 1 ----
    agg_kernel<<<4096, 256, 0, stream>>>(x, rowptr, csr, mean, N);
    lin_gemm_kernel<<<512, 256, 0, stream>>>(mean, x, W1l, W1r, b1, h, N, 1);

    // ---- layer 2 (reuse CSR) ----
    agg_kernel<<<4096, 256, 0, stream>>>(h, rowptr, csr, mean, N);
    lin_gemm_kernel<<<512, 256, 0, stream>>>(mean, h, W2l, W2r, b2, out, N, 0);
}

// Round 6
// 305.232 us; speedup vs baseline: 3.4276x; 1.0906x over previous
//
#include <hip/hip_runtime.h>

#define D 64
#define BSHIFT 9              // 512 nodes per bucket
#define BNODES (1 << BSHIFT)
#define NBK_MAX 512           // supports N up to 262144

// ---------- bf16 helpers (bit-exact RNE pack, shift-based unpack) ----------
__device__ __forceinline__ unsigned int f2bf_rne(float f) {
    unsigned int b = __float_as_uint(f);
    return (b + 0x7fffu + ((b >> 16) & 1u)) >> 16;
}
__device__ __forceinline__ unsigned int pack_bf(float lo, float hi) {
    return f2bf_rne(lo) | (f2bf_rne(hi) << 16);
}
__device__ __forceinline__ float bflo(unsigned int u) { return __uint_as_float(u << 16); }
__device__ __forceinline__ float bfhi(unsigned int u) { return __uint_as_float(u & 0xffff0000u); }

// ---------- zero int region ----------
__global__ void zeroi_kernel(int* __restrict__ p, int n) {
    int i = blockIdx.x * blockDim.x + threadIdx.x;
    if (i < n) p[i] = 0;
}

// ---------- cast fp32 features -> packed bf16 (2 feats per uint) ----------
__global__ void cast_kernel(const float4* __restrict__ xin, uint2* __restrict__ xb, int n4) {
    int i = blockIdx.x * blockDim.x + threadIdx.x;
    int stride = gridDim.x * blockDim.x;
    for (; i < n4; i += stride) {
        float4 v = xin[i];
        uint2 o;
        o.x = pack_bf(v.x, v.y);
        o.y = pack_bf(v.z, v.w);
        xb[i] = o;
    }
}

// ---------- phase 1: per-(bucket,group) histogram. group = blockIdx&7 (~XCD) ----------
__global__ __launch_bounds__(256) void hist2_kernel(const int* __restrict__ dst,
                                                    int* __restrict__ cnt2,
                                                    int E, int NBK, int CE) {
    __shared__ int lh[NBK_MAX];
    for (int k = threadIdx.x; k < NBK; k += 256) lh[k] = 0;
    __syncthreads();
    int b = blockIdx.x, g = b & 7;
    int beg = b * CE, end = min(beg + CE, E);
    for (int e = beg + threadIdx.x; e < end; e += 256)
        atomicAdd(&lh[dst[e] >> BSHIFT], 1);
    __syncthreads();
    for (int k = threadIdx.x; k < NBK; k += 256)
        if (lh[k]) atomicAdd(&cnt2[(k << 3) | g], lh[k]);
}

// ---------- phase 2: exclusive scan of cnt2[NBK*8] -> cur2 + bstart ----------
__global__ __launch_bounds__(256) void scan2k_kernel(const int* __restrict__ cnt2,
                                                     int* __restrict__ cur2,
                                                     int* __restrict__ bstart, int NBK) {
    __shared__ int s[256];
    int n = NBK << 3;
    int tid = threadIdx.x;
    int base = tid * 8;
    int loc[8];
    int sum = 0;
    for (int j = 0; j < 8; ++j) {
        int idx = base + j;
        int v = (idx < n) ? cnt2[idx] : 0;
        loc[j] = sum;
        sum += v;
    }
    s[tid] = sum;
    __syncthreads();
    for (int off = 1; off < 256; off <<= 1) {
        int t = (tid >= off) ? s[tid - off] : 0;
        __syncthreads();
        s[tid] += t;
        __syncthreads();
    }
    int ebase = s[tid] - sum;
    for (int j = 0; j < 8; ++j) {
        int idx = base + j;
        if (idx < n) cur2[idx] = ebase + loc[j];
    }
    if (tid < NBK) bstart[tid] = ebase;
    if (tid == 0) bstart[NBK] = s[255];
}

// ---------- phase 3: scatter packed (src | dst_low<<17) records ----------
__global__ __launch_bounds__(256) void binscatter_kernel(
    const int* __restrict__ src, const int* __restrict__ dst,
    int* __restrict__ cur2, unsigned int* __restrict__ pairs,
    int E, int NBK, int CE) {
    __shared__ int lh[NBK_MAX];
    __shared__ int lbase[NBK_MAX];
    for (int k = threadIdx.x; k < NBK; k += 256) lh[k] = 0;
    __syncthreads();
    int b = blockIdx.x, g = b & 7;
    int beg = b * CE, end = min(beg + CE, E);
    for (int e = beg + threadIdx.x; e < end; e += 256)
        atomicAdd(&lh[dst[e] >> BSHIFT], 1);
    __syncthreads();
    for (int k = threadIdx.x; k < NBK; k += 256) {
        int c = lh[k];
        if (c) lbase[k] = atomicAdd(&cur2[(k << 3) | g], c);
        lh[k] = 0;
    }
    __syncthreads();
    for (int e = beg + threadIdx.x; e < end; e += 256) {
        int d = dst[e];
        int k = d >> BSHIFT;
        int r = atomicAdd(&lh[k], 1);
        pairs[lbase[k] + r] = (unsigned int)src[e] | ((unsigned int)(d & (BNODES - 1)) << 17);
    }
}

// ---------- phase 4: one workgroup per bucket -> rowptr + bucket-local csr ----------
__global__ __launch_bounds__(256) void csr_build_kernel(
    const unsigned int* __restrict__ pairs, const int* __restrict__ bstart,
    int* __restrict__ rowptr, int* __restrict__ csr, int N, int NBK) {
    __shared__ int lcnt[BNODES];
    __shared__ int lofs[BNODES];
    __shared__ int s[256];
    int k = blockIdx.x;
    int tid = threadIdx.x;
    int node0 = k << BSHIFT;
    int nnodes = min(BNODES, N - node0);
    int rbeg = bstart[k], rend = bstart[k + 1];

    for (int j = tid; j < BNODES; j += 256) lcnt[j] = 0;
    __syncthreads();
    for (int i = rbeg + tid; i < rend; i += 256)
        atomicAdd(&lcnt[pairs[i] >> 17], 1);
    __syncthreads();
    int v0 = lcnt[2 * tid], v1 = lcnt[2 * tid + 1];
    int ps = v0 + v1;
    s[tid] = ps;
    __syncthreads();
    for (int off = 1; off < 256; off <<= 1) {
        int t = (tid >= off) ? s[tid - off] : 0;
        __syncthreads();
        s[tid] += t;
        __syncthreads();
    }
    int ebase = s[tid] - ps;
    lofs[2 * tid] = ebase;
    lofs[2 * tid + 1] = ebase + v0;
    __syncthreads();
    for (int j = tid; j < nnodes; j += 256) {
        int p = rbeg + lofs[j];
        rowptr[node0 + j] = p;
        lcnt[j] = p;
    }
    if (k == NBK - 1 && tid == 0) rowptr[N] = rend;
    __syncthreads();
    for (int i = rbeg + tid; i < rend; i += 256) {
        unsigned int rec = pairs[i];
        int j = rec >> 17;
        int pos = atomicAdd(&lcnt[j], 1);
        csr[pos] = (int)(rec & 0x1FFFFu);
    }
}

// ---------- aggregation, bf16: 2 nodes per wave; lane = feature pair (4B loads) ----------
__global__ __launch_bounds__(256) void agg_bf_kernel(
    const unsigned int* __restrict__ xb, const int* __restrict__ rowptr,
    const int* __restrict__ csr, unsigned int* __restrict__ meanb, int N) {
    int lane = threadIdx.x & 63;
    int half = lane >> 5;       // which of the wave's 2 nodes
    int fl = lane & 31;         // feature pair index (features 2fl, 2fl+1)
    int wid = blockIdx.x * (blockDim.x >> 6) + (threadIdx.x >> 6);
    int nwaves = gridDim.x * (blockDim.x >> 6);
    int npairs = (N + 1) >> 1;

    for (int p = wid; p < npairs; p += nwaves) {
        int node = p * 2 + half;
        bool valid = node < N;
        int beg = 0, end = 0;
        if (valid) { beg = rowptr[node]; end = rowptr[node + 1]; }
        float s0 = 0.f, s1 = 0.f;
        int j = beg;
        for (; j + 4 <= end; j += 4) {
            int i0 = csr[j], i1 = csr[j + 1], i2 = csr[j + 2], i3 = csr[j + 3];
            unsigned int u0 = xb[i0 * 32 + fl];
            unsigned int u1 = xb[i1 * 32 + fl];
            unsigned int u2 = xb[i2 * 32 + fl];
            unsigned int u3 = xb[i3 * 32 + fl];
            s0 += bflo(u0) + bflo(u1) + bflo(u2) + bflo(u3);
            s1 += bfhi(u0) + bfhi(u1) + bfhi(u2) + bfhi(u3);
        }
        for (; j < end; ++j) {
            unsigned int u = xb[csr[j] * 32 + fl];
            s0 += bflo(u);
            s1 += bfhi(u);
        }
        if (valid) {
            float inv = 1.0f / fmaxf((float)(end - beg), 1.0f);
            meanb[node * 32 + fl] = pack_bf(s0 * inv, s1 * inv);
        }
    }
}

// ---------- fused linear as LDS-tiled fp32 GEMM, bf16 in, fp32-and/or-bf16 out ----------
// out[n][f] = relu?( sum_k Wl[f][k]*mean[n][k] + sum_k Wr[f][k]*x[n][k] + b[f] )
#define WT_S 68    // Wt row stride (floats): 272B -> b128-aligned
#define AN_S 132   // An row stride (floats): 528B -> b128-aligned
__global__ __launch_bounds__(256) void lin_gemm_kernel(
    const unsigned int* __restrict__ meanb, const unsigned int* __restrict__ xb,
    const float* __restrict__ Wl, const float* __restrict__ Wr,
    const float* __restrict__ bias,
    float* __restrict__ outf, unsigned int* __restrict__ outb, int N, int relu) {
    __shared__ float Wt[128 * WT_S];
    __shared__ float An[64 * AN_S];
    int tid = threadIdx.x;

    // stage Wt (transposed weights), once per block
#pragma unroll
    for (int i = 0; i < 8; ++i) {
        int L = i * 256 + tid;
        int m = L >> 10;
        int r = L & 1023;
        int f = r >> 4;
        int kq = r & 15;
        const float* Wsrc = m ? Wr : Wl;
        float4 v = *(const float4*)(Wsrc + f * 64 + kq * 4);
        int kb = m * 64 + kq * 4;
        Wt[(kb + 0) * WT_S + f] = v.x;
        Wt[(kb + 1) * WT_S + f] = v.y;
        Wt[(kb + 2) * WT_S + f] = v.z;
        Wt[(kb + 3) * WT_S + f] = v.w;
    }

    int f0  = (tid & 15) * 4;   // output quad
    int nl0 = (tid >> 4) * 4;   // node quad (local)
    float4 bv = *(const float4*)(bias + f0);

    int numTiles = (N + 63) >> 6;
    for (int t = blockIdx.x; t < numTiles; t += gridDim.x) {
        int node0 = t << 6;
        __syncthreads();
        // stage An: 64 nodes x 128 k, from bf16 sources (8B loads, coalesced)
#pragma unroll
        for (int i = 0; i < 8; ++i) {
            int L = i * 256 + tid;
            int kq = L & 15;
            int h  = (L >> 4) & 1;      // 0 = mean, 1 = x
            int nl = L >> 5;
            int n = node0 + nl;
            float4 v = make_float4(0.f, 0.f, 0.f, 0.f);
            if (n < N) {
                const unsigned int* row = (h ? xb : meanb) + n * 32 + kq * 2;
                uint2 u = *(const uint2*)row;
                v = make_float4(bflo(u.x), bfhi(u.x), bflo(u.y), bfhi(u.y));
            }
            *(float4*)&An[nl * AN_S + h * 64 + kq * 4] = v;
        }
        __syncthreads();
        float acc00=0,acc01=0,acc02=0,acc03=0;
        float acc10=0,acc11=0,acc12=0,acc13=0;
        float acc20=0,acc21=0,acc22=0,acc23=0;
        float acc30=0,acc31=0,acc32=0,acc33=0;
#pragma unroll 4
        for (int k = 0; k < 128; ++k) {
            float4 w = *(const float4*)&Wt[k * WT_S + f0];
            float a0 = An[(nl0 + 0) * AN_S + k];
            float a1 = An[(nl0 + 1) * AN_S + k];
            float a2 = An[(nl0 + 2) * AN_S + k];
            float a3 = An[(nl0 + 3) * AN_S + k];
            acc00 += a0 * w.x; acc01 += a0 * w.y; acc02 += a0 * w.z; acc03 += a0 * w.w;
            acc10 += a1 * w.x; acc11 += a1 * w.y; acc12 += a1 * w.z; acc13 += a1 * w.w;
            acc20 += a2 * w.x; acc21 += a2 * w.y; acc22 += a2 * w.z; acc23 += a2 * w.w;
            acc30 += a3 * w.x; acc31 += a3 * w.y; acc32 += a3 * w.z; acc33 += a3 * w.w;
        }
        float r0[4] = {acc00+bv.x, acc01+bv.y, acc02+bv.z, acc03+bv.w};
        float r1[4] = {acc10+bv.x, acc11+bv.y, acc12+bv.z, acc13+bv.w};
        float r2[4] = {acc20+bv.x, acc21+bv.y, acc22+bv.z, acc23+bv.w};
        float r3[4] = {acc30+bv.x, acc31+bv.y, acc32+bv.z, acc33+bv.w};
        if (relu) {
#pragma unroll
            for (int q = 0; q < 4; ++q) {
                r0[q] = fmaxf(r0[q], 0.f); r1[q] = fmaxf(r1[q], 0.f);
                r2[q] = fmaxf(r2[q], 0.f); r3[q] = fmaxf(r3[q], 0.f);
            }
        }
        int nb = node0 + nl0;
        if (outf) {
            if (nb + 0 < N) *(float4*)(outf + (long long)(nb + 0) * D + f0) = make_float4(r0[0], r0[1], r0[2], r0[3]);
            if (nb + 1 < N) *(float4*)(outf + (long long)(nb + 1) * D + f0) = make_float4(r1[0], r1[1], r1[2], r1[3]);
            if (nb + 2 < N) *(float4*)(outf + (long long)(nb + 2) * D + f0) = make_float4(r2[0], r2[1], r2[2], r2[3]);
            if (nb + 3 < N) *(float4*)(outf + (long long)(nb + 3) * D + f0) = make_float4(r3[0], r3[1], r3[2], r3[3]);
        }
        if (outb) {
            int fo = f0 >> 1;  // uint offset within 32-uint row (even -> 8B aligned)
            if (nb + 0 < N) *(uint2*)(outb + (nb + 0) * 32 + fo) = make_uint2(pack_bf(r0[0], r0[1]), pack_bf(r0[2], r0[3]));
            if (nb + 1 < N) *(uint2*)(outb + (nb + 1) * 32 + fo) = make_uint2(pack_bf(r1[0], r1[1]), pack_bf(r1[2], r1[3]));
            if (nb + 2 < N) *(uint2*)(outb + (nb + 2) * 32 + fo) = make_uint2(pack_bf(r2[0], r2[1]), pack_bf(r2[2], r2[3]));
            if (nb + 3 < N) *(uint2*)(outb + (nb + 3) * 32 + fo) = make_uint2(pack_bf(r3[0], r3[1]), pack_bf(r3[2], r3[3]));
        }
        __syncthreads();
    }
}

extern "C" void kernel_launch(void* const* d_in, const int* in_sizes, int n_in,
                              void* d_out, int out_size, void* d_ws, size_t ws_size,
                              hipStream_t stream) {
    const float* x   = (const float*)d_in[0];
    const int* ei    = (const int*)d_in[1];
    const float* W1l = (const float*)d_in[2];
    const float* W1r = (const float*)d_in[3];
    const float* b1  = (const float*)d_in[4];
    const float* W2l = (const float*)d_in[5];
    const float* W2r = (const float*)d_in[6];
    const float* b2  = (const float*)d_in[7];

    const int E = in_sizes[1] / 2;
    const int N = in_sizes[0] / D;     // requires N <= 131072 (17-bit packing)
    const int* src  = ei;
    const int* dstp = ei + E;
    const int NBK = (N + BNODES - 1) >> BSHIFT;
    const int G1 = 512;
    const int CE = (E + G1 - 1) / G1;

    char* ws = (char*)d_ws;
    size_t off = 0;
    auto alloc = [&](size_t bytes) { void* p = ws + off; off = (off + bytes + 255) & ~(size_t)255; return p; };
    int* cnt2           = (int*)alloc((size_t)(NBK * 8) * 4);
    int* cur2           = (int*)alloc((size_t)(NBK * 8) * 4);
    int* bstart         = (int*)alloc((size_t)(NBK + 1) * 4);
    int* rowptr         = (int*)alloc((size_t)(N + 1) * 4);
    unsigned int* pairs = (unsigned int*)alloc((size_t)E * 4);
    int* csr            = (int*)alloc((size_t)E * 4);
    unsigned int* xb    = (unsigned int*)alloc((size_t)N * 32 * 4);  // bf16 x, packed
    unsigned int* meanb = (unsigned int*)alloc((size_t)N * 32 * 4);  // bf16 mean
    unsigned int* hb    = (unsigned int*)alloc((size_t)N * 32 * 4);  // bf16 h

    float* out = (float*)d_out;

    // ---- cast features to bf16 ----
    cast_kernel<<<2048, 256, 0, stream>>>((const float4*)x, (uint2*)xb, N * 16);

    // ---- CSR build: bucket counting sort, dense writes ----
    zeroi_kernel<<<(NBK * 8 + 255) / 256, 256, 0, stream>>>(cnt2, NBK * 8);
    hist2_kernel<<<G1, 256, 0, stream>>>(dstp, cnt2, E, NBK, CE);
    scan2k_kernel<<<1, 256, 0, stream>>>(cnt2, cur2, bstart, NBK);
    binscatter_kernel<<<G1, 256, 0, stream>>>(src, dstp, cur2, pairs, E, NBK, CE);
    csr_build_kernel<<<NBK, 256, 0, stream>>>(pairs, bstart, rowptr, csr, N, NBK);

    // ---- layer 1: gather bf16 x -> mean; GEMM emits bf16 h only ----
    agg_bf_kernel<<<4096, 256, 0, stream>>>(xb, rowptr, csr, meanb, N);
    lin_gemm_kernel<<<512, 256, 0, stream>>>(meanb, xb, W1l, W1r, b1, nullptr, hb, N, 1);

    // ---- layer 2: gather bf16 h -> mean; GEMM emits fp32 out ----
    agg_bf_kernel<<<4096, 256, 0, stream>>>(hb, rowptr, csr, meanb, N);
    lin_gemm_kernel<<<512, 256, 0, stream>>>(meanb, hb, W2l, W2r, b2, out, nullptr, N, 0);
}